// Round 1
// baseline (272.798 us; speedup 1.0000x reference)
//
#include <hip/hip_runtime.h>

// Problem constants (match reference)
#define BATCH 8192
#define TSTEPS 200
#define FEAT 16
#define HID 32
#define GATES 128   // 4*HID, Keras order: i | f | cc | o
#define DOUT 60
#define ROWS 16     // batch rows per wave (one MFMA M-tile)
#define HSTRIDE 40  // LDS h row stride in halves (80 B, breaks row-parity conflicts)

typedef __fp16 half2v __attribute__((ext_vector_type(2)));
typedef __fp16 half4v __attribute__((ext_vector_type(4)));
typedef __fp16 half8v __attribute__((ext_vector_type(8)));
typedef float  float4v __attribute__((ext_vector_type(4)));

// Weights for i/f/o gates are pre-scaled by -log2(e) at frag load, so
// sigmoid(g) = 1 / (1 + exp2(g_scaled)) -- one mul saved per gate per step.
__device__ __forceinline__ float sig_pre(float v) {
    return __builtin_amdgcn_rcpf(1.0f + __builtin_amdgcn_exp2f(v));
}

__device__ __forceinline__ half4v pack4(float4 v) {
    half2v lo = __builtin_amdgcn_cvt_pkrtz(v.x, v.y);
    half2v hi = __builtin_amdgcn_cvt_pkrtz(v.z, v.w);
    half4v r;
    r[0] = lo[0]; r[1] = lo[1]; r[2] = hi[0]; r[3] = hi[1];
    return r;
}

// Single-wave persistent LSTM tile: one wave owns 16 batch rows AND all
// 128 gate columns (8 col-tiles of 16). No __syncthreads anywhere.
//   h·U  : 8 x mfma_f32_16x16x32_f16 (K = 32 hidden units)
//   x·W  : 8 x mfma_f32_16x16x16_f16 (K = 16 feats, exact fit) -- issued
//          one step AHEAD (h-independent), hides under the h·U chain.
//   h exchange: wave-internal LDS round trip (8 ds_write_b16 + 1
//          ds_read_b128); in-wave DS ordering + wave_barrier() fence.
// Fragment layouts (gfx950, verified in prior passing kernel):
//   16x16x32 A[m][k]: m=lane&15, k=(lane>>4)*8+j ; B[k][n]: n=lane&15, same k
//   16x16x16 A[m][k]: m=lane&15, k=(lane>>4)*4+j ; B[k][n]: n=lane&15, same k
//   D[m][n]: n=lane&15, m=(lane>>4)*4+r
// Epilogue ownership: lane = 16g+n16 holds rows g*4+r, units n16 and n16+16,
// with all four gates (tiles gate*2+u) lane-local.
__global__ __launch_bounds__(64, 1) void lstm_mfma(
    const float* __restrict__ x,    // [B, T, F]
    const float* __restrict__ W,    // [F, 128]
    const float* __restrict__ U,    // [H, 128]
    const float* __restrict__ bg,   // [128]
    const float* __restrict__ W1,   // [H, 60]
    const float* __restrict__ b1,   // [60]
    const float* __restrict__ W2,   // [H, 60]
    const float* __restrict__ b2,   // [60]
    float* __restrict__ out)        // [2 * B * 60] (long || lat)
{
    const int lane = threadIdx.x;   // 64-thread block = 1 wave
    const int n16  = lane & 15;
    const int g    = lane >> 4;
    const int b0   = blockIdx.x * ROWS;

    __shared__ __align__(16) __fp16 hbuf[ROWS * HSTRIDE];

    // ---- stationary B-frags: U (K=32) and W (K=16); fold -log2e into i,f,o ----
    half8v bU[8];
    half4v bW[8];
    float  bias[8];
    #pragma unroll
    for (int tt = 0; tt < 8; tt++) {
        const int col = tt * 16 + n16;                     // gate column
        const float s = ((tt >> 1) == 2) ? 1.0f : -1.44269504088896340736f;
        half8v u8;
        #pragma unroll
        for (int j = 0; j < 8; j++)
            u8[j] = (__fp16)(U[(g * 8 + j) * GATES + col] * s);
        bU[tt] = u8;
        half4v w4;
        #pragma unroll
        for (int j = 0; j < 4; j++)
            w4[j] = (__fp16)(W[(g * 4 + j) * GATES + col] * s);
        bW[tt] = w4;
        bias[tt] = bg[col] * s;
    }

    // zero h_0
    #pragma unroll
    for (int i = lane; i < ROWS * HSTRIDE; i += 64) hbuf[i] = (__fp16)0.f;
    __builtin_amdgcn_wave_barrier();   // fence zero-init writes vs first read

    // x source: lane reads x[b0+n16][t][g*4 .. g*4+3] (16 B)
    const float* xrow = x + (size_t)(b0 + n16) * TSTEPS * FEAT + g * 4;

    float4 x0v = *reinterpret_cast<const float4*>(xrow);               // x_0
    float4 xf0 = *reinterpret_cast<const float4*>(xrow + FEAT);        // x_1
    float4 xf1 = *reinterpret_cast<const float4*>(xrow + 2 * FEAT);    // x_2

    // accx(0) = bias + x_0·W
    float4v accx[8];
    {
        half4v ax0 = pack4(x0v);
        #pragma unroll
        for (int tt = 0; tt < 8; tt++) {
            float4v a = {bias[tt], bias[tt], bias[tt], bias[tt]};
            accx[tt] = __builtin_amdgcn_mfma_f32_16x16x16f16(ax0, bW[tt], a, 0, 0, 0);
        }
    }

    float cst[2][4] = {{0.f, 0.f, 0.f, 0.f}, {0.f, 0.f, 0.f, 0.f}};

    // One step. XN holds x_{T+1} on entry; refilled with x_{T+3}.
    // Critical path: ds_read h_T -> 8 mfma -> epilogue -> 8 ds_write h_{T+1}.
    // accx(T+1) mfmas + global prefetch are independent and overlap it.
#define STEP(XN, T)                                                           \
    {                                                                         \
        half8v ha = *reinterpret_cast<const half8v*>(                         \
            &hbuf[n16 * HSTRIDE + g * 8]);                                    \
        float4v acc[8];                                                       \
        _Pragma("unroll")                                                     \
        for (int tt = 0; tt < 8; tt++)                                        \
            acc[tt] = __builtin_amdgcn_mfma_f32_16x16x32_f16(                 \
                ha, bU[tt], accx[tt], 0, 0, 0);                               \
        if ((T) + 1 < TSTEPS) {                                               \
            half4v ax = pack4(XN);                                            \
            _Pragma("unroll")                                                 \
            for (int tt = 0; tt < 8; tt++) {                                  \
                float4v a = {bias[tt], bias[tt], bias[tt], bias[tt]};         \
                accx[tt] = __builtin_amdgcn_mfma_f32_16x16x16f16(             \
                    ax, bW[tt], a, 0, 0, 0);                                  \
            }                                                                 \
        }                                                                     \
        if ((T) + 3 < TSTEPS)                                                 \
            XN = *reinterpret_cast<const float4*>(                            \
                xrow + (size_t)((T) + 3) * FEAT);                             \
        _Pragma("unroll")                                                     \
        for (int u = 0; u < 2; u++) {                                         \
            _Pragma("unroll")                                                 \
            for (int r = 0; r < 4; r++) {                                     \
                float iv = sig_pre(acc[0 + u][r]);                            \
                float fv = sig_pre(acc[2 + u][r]);                            \
                float cc = acc[4 + u][r];                                     \
                float ov = sig_pre(acc[6 + u][r]);                            \
                float cn = fmaf(fv, cst[u][r], iv * fmaxf(cc, 0.f));          \
                cst[u][r] = cn;                                               \
                float hn = ov * fmaxf(cn, 0.f);                               \
                hbuf[(g * 4 + r) * HSTRIDE + u * 16 + n16] = (__fp16)hn;      \
            }                                                                 \
        }                                                                     \
        __builtin_amdgcn_wave_barrier(); /* writes(T+1) before read(T+1) */   \
    }

    for (int t = 0; t < TSTEPS; t += 2) {
        STEP(xf0, t);
        STEP(xf1, t + 1);
    }
#undef STEP

    // ---- heads: out = h_T @ W1/W2 + b (fp32, h from LDS) ----
    for (int idx = lane; idx < ROWS * DOUT; idx += 64) {
        const int row = idx / DOUT;
        const int d   = idx - row * DOUT;
        float s1 = b1[d], s2 = b2[d];
        #pragma unroll 8
        for (int k = 0; k < HID; k++) {
            float hv = (float)hbuf[row * HSTRIDE + k];
            s1 = fmaf(hv, W1[k * DOUT + d], s1);
            s2 = fmaf(hv, W2[k * DOUT + d], s2);
        }
        out[(size_t)(b0 + row) * DOUT + d] = s1;
        out[(size_t)BATCH * DOUT + (size_t)(b0 + row) * DOUT + d] = s2;
    }
}

extern "C" void kernel_launch(void* const* d_in, const int* in_sizes, int n_in,
                              void* d_out, int out_size, void* d_ws, size_t ws_size,
                              hipStream_t stream) {
    const float* x  = (const float*)d_in[0];
    const float* W  = (const float*)d_in[1];
    const float* U  = (const float*)d_in[2];
    const float* bg = (const float*)d_in[3];
    const float* W1 = (const float*)d_in[4];
    const float* b1 = (const float*)d_in[5];
    const float* W2 = (const float*)d_in[6];
    const float* b2 = (const float*)d_in[7];
    float* out = (float*)d_out;

    dim3 grid(BATCH / ROWS);   // 512 blocks x 1 wave, fully independent
    dim3 block(64);
    lstm_mfma<<<grid, block, 0, stream>>>(x, W, U, bg, W1, b1, W2, b2, out);
}

// Round 2
// 264.918 us; speedup vs baseline: 1.0297x; 1.0297x over previous
//
#include <hip/hip_runtime.h>

// Problem constants (match reference)
#define BATCH 8192
#define TSTEPS 200
#define FEAT 16
#define HID 32
#define GATES 128   // 4*HID, Keras order: i | f | cc | o
#define DOUT 60
#define ROWS 16     // batch rows per wave (one MFMA N-tile, transposed form)
#define HSTRIDE 40  // LDS h row stride in halves (final head pass only)

typedef __fp16 half2v __attribute__((ext_vector_type(2)));
typedef __fp16 half4v __attribute__((ext_vector_type(4)));
typedef __fp16 half8v __attribute__((ext_vector_type(8)));
typedef float  float4v __attribute__((ext_vector_type(4)));

// Weights/bias for i/f/o gates pre-scaled by -log2(e):
// sigmoid(x) = 1 / (1 + exp2(-log2e * x))
__device__ __forceinline__ float sig_pre(float v) {
    return __builtin_amdgcn_rcpf(1.0f + __builtin_amdgcn_exp2f(v));
}

__device__ __forceinline__ half2v pkrtz(float a, float b) {
    return __builtin_amdgcn_cvt_pkrtz(a, b);
}

__device__ __forceinline__ half4v pack4(float4 v) {
    half2v lo = pkrtz(v.x, v.y);
    half2v hi = pkrtz(v.z, v.w);
    half4v r;
    r[0] = lo[0]; r[1] = lo[1]; r[2] = hi[0]; r[3] = hi[1];
    return r;
}

// Permuted gate-column map. Tile tt (0..7) = gate-type (tt>>1: i,f,cc,o) x
// half (tt&1). Within a tile, column m maps to unit 8*(m>>2) + (m&3) + 4*half.
// Chosen so that lane (g,n16) -- which owns D rows m = 4g+r -- produces h for
// units {8g+r} (lo) and {8g+4+r} (hi) of row n16: exactly the k-range
// 8g..8g+7 its own next-step B-fragment needs. Recurrence = register-local.
__device__ __forceinline__ int gcol(int tt, int m) {
    return 32 * (tt >> 1) + 8 * (m >> 2) + (m & 3) + 4 * (tt & 1);
}

// Register-resident persistent LSTM: one wave owns 16 batch rows and all 128
// gate columns, computed TRANSPOSED: gates^T = U^T·h^T (8x mfma 16x16x32) and
// W^T·x^T (8x mfma 16x16x16, issued one step ahead). With the gcol column
// permutation, the next step's h B-frag is each lane's own epilogue output --
// zero LDS / cross-lane traffic in the 200-step loop.
// Fragment layouts (gfx950, verified by prior passing kernels; A/B symmetric):
//   16x16x32 A[m][k]: m=lane&15, k=(lane>>4)*8+j ; B[k][n]: n=lane&15, same k
//   16x16x16 A[m][k]: m=lane&15, k=(lane>>4)*4+j ; B[k][n]: n=lane&15, same k
//   D[m][n]: n=lane&15, m=(lane>>4)*4+r
__global__ __launch_bounds__(64, 1) void lstm_mfma(
    const float* __restrict__ x,    // [B, T, F]
    const float* __restrict__ W,    // [F, 128]
    const float* __restrict__ U,    // [H, 128]
    const float* __restrict__ bg,   // [128]
    const float* __restrict__ W1,   // [H, 60]
    const float* __restrict__ b1,   // [60]
    const float* __restrict__ W2,   // [H, 60]
    const float* __restrict__ b2,   // [60]
    float* __restrict__ out)        // [2 * B * 60] (long || lat)
{
    const int lane = threadIdx.x;   // 64-thread block = 1 wave
    const int n16  = lane & 15;     // batch row within tile (MFMA n / B-frag n)
    const int g    = lane >> 4;     // k-quad / D-row-quad
    const int b0   = blockIdx.x * ROWS;

    __shared__ __align__(16) __fp16 hbuf[ROWS * HSTRIDE];  // head pass only

    // ---- stationary A-frags: U^T (K=32), W^T (K=16), bias (per D-row) ----
    half8v  bU[8];
    half4v  bW[8];
    float4v bias[8];
    #pragma unroll
    for (int tt = 0; tt < 8; tt++) {
        const float s = ((tt >> 1) == 2) ? 1.0f : -1.44269504088896340736f;
        const int colA = gcol(tt, n16);     // gate col this lane's A-frag row
        half8v u8;
        #pragma unroll
        for (int j = 0; j < 8; j++)
            u8[j] = (__fp16)(U[(8 * g + j) * GATES + colA] * s);
        bU[tt] = u8;
        half4v w4;
        #pragma unroll
        for (int j = 0; j < 4; j++)
            w4[j] = (__fp16)(W[(4 * g + j) * GATES + colA] * s);
        bW[tt] = w4;
        float4v bv;
        #pragma unroll
        for (int r = 0; r < 4; r++)
            bv[r] = bg[gcol(tt, 4 * g + r)] * s;   // bias for D row m=4g+r
        bias[tt] = bv;
    }

    // x source: lane reads x[b0+n16][t][4g .. 4g+3] (B-frag of x^T)
    const float* xrow = x + (size_t)(b0 + n16) * TSTEPS * FEAT + 4 * g;

    float4 xf0 = *reinterpret_cast<const float4*>(xrow + FEAT);        // x_1
    float4 xf1 = *reinterpret_cast<const float4*>(xrow + 2 * FEAT);    // x_2

    // accx(0) = bias + W^T·x_0^T
    float4v accx[8];
    {
        half4v ax0 = pack4(*reinterpret_cast<const float4*>(xrow));
        #pragma unroll
        for (int tt = 0; tt < 8; tt++)
            accx[tt] = __builtin_amdgcn_mfma_f32_16x16x16f16(
                bW[tt], ax0, bias[tt], 0, 0, 0);
    }

    union { half8v v; half2v h2[4]; } hB;          // h_t B-frag, register-local
    hB.v = (half8v)(__fp16)0.f;                    // h_0 = 0
    float cst[2][4] = {{0.f, 0.f, 0.f, 0.f}, {0.f, 0.f, 0.f, 0.f}};

    // One step. XN holds x_{T+1} on entry; refilled with x_{T+3}.
    // Critical path: 8 mfma (h·U) -> gate epilogue (trans) -> pkrtz -> next.
    // accx(T+1) mfmas + x prefetch are h-independent and overlap the chain.
#define STEP(XN, T)                                                           \
    {                                                                         \
        float4v acc[8];                                                       \
        _Pragma("unroll")                                                     \
        for (int tt = 0; tt < 8; tt++)                                        \
            acc[tt] = __builtin_amdgcn_mfma_f32_16x16x32_f16(                 \
                bU[tt], hB.v, accx[tt], 0, 0, 0);                             \
        if ((T) + 1 < TSTEPS) {                                               \
            half4v ax = pack4(XN);                                            \
            _Pragma("unroll")                                                 \
            for (int tt = 0; tt < 8; tt++)                                    \
                accx[tt] = __builtin_amdgcn_mfma_f32_16x16x16f16(             \
                    bW[tt], ax, bias[tt], 0, 0, 0);                           \
        }                                                                     \
        if ((T) + 3 < TSTEPS)                                                 \
            XN = *reinterpret_cast<const float4*>(                            \
                xrow + (size_t)((T) + 3) * FEAT);                             \
        _Pragma("unroll")                                                     \
        for (int hf = 0; hf < 2; hf++) {                                      \
            float hn[4];                                                      \
            _Pragma("unroll")                                                 \
            for (int r = 0; r < 4; r++) {                                     \
                float iv = sig_pre(acc[0 + hf][r]);                           \
                float fv = sig_pre(acc[2 + hf][r]);                           \
                float cc = acc[4 + hf][r];                                    \
                float ov = sig_pre(acc[6 + hf][r]);                           \
                float cn = fmaf(fv, cst[hf][r], iv * fmaxf(cc, 0.f));         \
                cst[hf][r] = cn;                                              \
                hn[r] = ov * fmaxf(cn, 0.f);                                  \
            }                                                                 \
            hB.h2[2 * hf]     = pkrtz(hn[0], hn[1]);                          \
            hB.h2[2 * hf + 1] = pkrtz(hn[2], hn[3]);                          \
        }                                                                     \
    }

    for (int t = 0; t < TSTEPS; t += 2) {
        STEP(xf0, t);
        STEP(xf1, t + 1);
    }
#undef STEP

    // ---- stage h_T to LDS (once), then heads: out = h_T @ W1/W2 + b ----
    // lane holds h_T for (row n16, units 8g..8g+7): contiguous 16B store.
    *reinterpret_cast<half8v*>(&hbuf[n16 * HSTRIDE + 8 * g]) = hB.v;
    __builtin_amdgcn_wave_barrier();   // in-wave DS ordering covers the reads

    for (int idx = lane; idx < ROWS * DOUT; idx += 64) {
        const int row = idx / DOUT;
        const int d   = idx - row * DOUT;
        float s1 = b1[d], s2 = b2[d];
        #pragma unroll 8
        for (int k = 0; k < HID; k++) {
            float hv = (float)hbuf[row * HSTRIDE + k];
            s1 = fmaf(hv, W1[k * DOUT + d], s1);
            s2 = fmaf(hv, W2[k * DOUT + d], s2);
        }
        out[(size_t)(b0 + row) * DOUT + d] = s1;
        out[(size_t)BATCH * DOUT + (size_t)(b0 + row) * DOUT + d] = s2;
    }
}

extern "C" void kernel_launch(void* const* d_in, const int* in_sizes, int n_in,
                              void* d_out, int out_size, void* d_ws, size_t ws_size,
                              hipStream_t stream) {
    const float* x  = (const float*)d_in[0];
    const float* W  = (const float*)d_in[1];
    const float* U  = (const float*)d_in[2];
    const float* bg = (const float*)d_in[3];
    const float* W1 = (const float*)d_in[4];
    const float* b1 = (const float*)d_in[5];
    const float* W2 = (const float*)d_in[6];
    const float* b2 = (const float*)d_in[7];
    float* out = (float*)d_out;

    dim3 grid(BATCH / ROWS);   // 512 blocks x 1 wave, fully independent
    dim3 block(64);
    lstm_mfma<<<grid, block, 0, stream>>>(x, W, U, bg, W1, b1, W2, b2, out);
}